// Round 5
// baseline (7122.396 us; speedup 1.0000x reference)
//
#include <hip/hip_runtime.h>
#include <stdint.h>
#include <stdio.h>

// Problem constants
#define B_    2
#define S_    2048
#define DM_   2048
#define NQ_   16
#define NKV_  4
#define DH_   128
#define DR_   64
#define DKV_  512
#define DQC_  1536
#define DT_   192
#define M_    4096   // B_*S_

__device__ __forceinline__ float cl(float f) {   // clamp diagnostic: inf/NaN -> +-3.38e38 signature
    return fminf(fmaxf(f, -3.38e38f), 3.38e38f);
}

// ---------------------------------------------------------------------------
// Tiled GEMM: C[M][N] = A[M][K] @ W[K][N], all fp32, VALU accumulate.
// 256 threads as 16x16; 64x64 C-tile; 4x4 micro-tile per thread; BK=32.
// ---------------------------------------------------------------------------
__global__ __launch_bounds__(256) void gemm_nt(const float* __restrict__ A,
                                               const float* __restrict__ W,
                                               float* __restrict__ C,
                                               int M, int N, int K) {
    __shared__ float lA[32][64];   // [k][m]
    __shared__ float lW[32][64];   // [k][n]
    const int tid = threadIdx.x;
    const int tx = tid & 15, ty = tid >> 4;
    const int m0 = blockIdx.y * 64, n0 = blockIdx.x * 64;
    float acc[4][4] = {};

    for (int kt = 0; kt < K; kt += 32) {
        __syncthreads();
        // A tile: 64 rows x 32 k-cols = 512 float4 segs, 2/thread (coalesced)
#pragma unroll
        for (int c = 0; c < 2; ++c) {
            int sg = c * 256 + tid;
            int r = sg >> 3, c4 = (sg & 7) * 4;
            float4 v = *(const float4*)(A + (size_t)(m0 + r) * K + kt + c4);
            lA[c4 + 0][r] = v.x; lA[c4 + 1][r] = v.y;
            lA[c4 + 2][r] = v.z; lA[c4 + 3][r] = v.w;
        }
        // W tile: 32 k-rows x 64 n-cols = 512 float4 segs, 2/thread (coalesced)
#pragma unroll
        for (int c = 0; c < 2; ++c) {
            int sg = c * 256 + tid;
            int rr = sg >> 4, n4 = (sg & 15) * 4;
            *(float4*)&lW[rr][n4] = *(const float4*)(W + (size_t)(kt + rr) * N + n0 + n4);
        }
        __syncthreads();
#pragma unroll
        for (int kk = 0; kk < 32; ++kk) {
            float4 a4 = *(const float4*)&lA[kk][ty * 4];
            float4 w4 = *(const float4*)&lW[kk][tx * 4];
            float a[4] = {a4.x, a4.y, a4.z, a4.w};
            float w[4] = {w4.x, w4.y, w4.z, w4.w};
#pragma unroll
            for (int i = 0; i < 4; ++i)
#pragma unroll
                for (int j = 0; j < 4; ++j)
                    acc[i][j] += a[i] * w[j];
        }
    }
#pragma unroll
    for (int i = 0; i < 4; ++i) {
        float* cp = C + (size_t)(m0 + ty * 4 + i) * N + n0 + tx * 4;
        float4 v = {cl(acc[i][0]), cl(acc[i][1]), cl(acc[i][2]), cl(acc[i][3])};
        *(float4*)cp = v;
    }
}

// ---------------------------------------------------------------------------
// RoPE Q, in place on qr[(b,s)][h*64+d] (fp32)
// ---------------------------------------------------------------------------
__global__ __launch_bounds__(256) void rope_q_inplace(float* __restrict__ qr,
                                                      const float* __restrict__ cosc,
                                                      const float* __restrict__ sinc,
                                                      const int* __restrict__ pos) {
    int t = blockIdx.x * 256 + threadIdx.x;          // t < 4096*16*32
    int d = t & 31, h = (t >> 5) & 15, rowi = t >> 9;
    int s = rowi & 2047;
    int p = pos[s];
    float c1 = cosc[p * 64 + d],      s1 = sinc[p * 64 + d];
    float c2 = cosc[p * 64 + 32 + d], s2 = sinc[p * 64 + 32 + d];
    float* base = qr + (size_t)rowi * 1024 + h * 64;
    float x1 = base[d];
    float x2 = base[d + 32];
    base[d]      = x1 * c1 - x2 * s1;   // out = x*cos + rotate_half(x)*sin
    base[d + 32] = x2 * c2 + x1 * s2;
}

// RoPE K: krr[(b,s)][kv*64+d] -> Krope[b][kv][s][64]  (= Output 2)
__global__ __launch_bounds__(256) void rope_k(const float* __restrict__ krr,
                                              const float* __restrict__ cosc,
                                              const float* __restrict__ sinc,
                                              const int* __restrict__ pos,
                                              float* __restrict__ Krope) {
    int t = blockIdx.x * 256 + threadIdx.x;          // t < 4096*4*32
    int d = t & 31, kv = (t >> 5) & 3, rowi = t >> 7;
    int b = rowi >> 11, s = rowi & 2047;
    int p = pos[s];
    float c1 = cosc[p * 64 + d],      s1 = sinc[p * 64 + d];
    float c2 = cosc[p * 64 + 32 + d], s2 = sinc[p * 64 + 32 + d];
    float x1 = krr[(size_t)rowi * 256 + kv * 64 + d];
    float x2 = krr[(size_t)rowi * 256 + kv * 64 + 32 + d];
    size_t ob = ((size_t)((b * NKV_ + kv) * S_) + s) * 64;
    Krope[ob + d]      = cl(x1 * c1 - x2 * s1);
    Krope[ob + 32 + d] = cl(x2 * c2 + x1 * s2);
}

// ---------------------------------------------------------------------------
// Causal GQA flash attention (fp32 VALU). 128 q-rows x 2 par-threads per block.
// grid (16 qtiles, 16 heads, 2 batch). Reads projection layouts directly:
// qc[(b,s)][h*128+d], qr[(b,s)][h*64+d], kc[(b,s)][kv*128+d],
// kr[b][kv][s][64], vv[(b,s)][kv*128+d].  Out: [(b,s)][h*128+d].
// ---------------------------------------------------------------------------
__global__ __launch_bounds__(256) void attn_kernel(const float* __restrict__ qc,
                                                   const float* __restrict__ qr,
                                                   const float* __restrict__ kc,
                                                   const float* __restrict__ kr,
                                                   const float* __restrict__ vv,
                                                   float* __restrict__ attn_out) {
    __shared__ __align__(16) float lK[32 * DT_];
    __shared__ __align__(16) float lV[32 * DH_];
    const int t = threadIdx.x;
    const int b = blockIdx.z;
    const int h = blockIdx.y;
    // balance causal work: batch 0 takes reversed qt order
    const int qt = (b == 0) ? (15 - (int)blockIdx.x) : (int)blockIdx.x;
    const int kv = h >> 2;
    const int i   = qt * 128 + (t >> 1);
    const int par = t & 1;
    const float sc = 0.07216878364870322f;   // 1/sqrt(192)

    // this thread's 96 Q dims (par=0: content 0..95; par=1: content 96..127 + rope 0..63)
    float q[96];
    if (par == 0) {
        const float* qp = qc + ((size_t)(b * S_ + i)) * 2048 + h * 128;
#pragma unroll
        for (int k = 0; k < 96; ++k) q[k] = qp[k] * sc;
    } else {
        const float* qp = qc + ((size_t)(b * S_ + i)) * 2048 + h * 128 + 96;
#pragma unroll
        for (int k = 0; k < 32; ++k) q[k] = qp[k] * sc;
        const float* qp2 = qr + ((size_t)(b * S_ + i)) * 1024 + h * 64;
#pragma unroll
        for (int k = 0; k < 64; ++k) q[32 + k] = qp2[k] * sc;
    }

    float O[64];
#pragma unroll
    for (int d = 0; d < 64; ++d) O[d] = 0.f;
    float mrun = -1e30f, lrun = 0.f;

    const int ntile = qt * 4 + 4;
    for (int tile = 0; tile < ntile; ++tile) {
        const int j0 = tile * 32;
        __syncthreads();
        {   // K content: 32 rows x 128 = 1024 float4 segs, 4/thread
            const float* kcb = kc + ((size_t)(b * S_ + j0)) * 512 + kv * 128;
#pragma unroll
            for (int c = 0; c < 4; ++c) {
                int sg = c * 256 + t, j = sg >> 5, d4 = (sg & 31) * 4;
                *(float4*)&lK[j * DT_ + d4] = *(const float4*)(kcb + (size_t)j * 512 + d4);
            }
        }
        {   // K rope: 32 rows x 64 = 512 segs, 2/thread
#pragma unroll
            for (int c = 0; c < 2; ++c) {
                int sg = c * 256 + t, j = sg >> 4, d4 = (sg & 15) * 4;
                *(float4*)&lK[j * DT_ + 128 + d4] =
                    *(const float4*)(kr + ((size_t)((b * NKV_ + kv) * S_) + j0 + j) * 64 + d4);
            }
        }
        {   // V: 32 rows x 128 = 1024 segs, 4/thread
            const float* vvp = vv + ((size_t)(b * S_ + j0)) * 512 + kv * 128;
#pragma unroll
            for (int c = 0; c < 4; ++c) {
                int sg = c * 256 + t, j = sg >> 5, d4 = (sg & 31) * 4;
                *(float4*)&lV[j * DH_ + d4] = *(const float4*)(vvp + (size_t)j * 512 + d4);
            }
        }
        __syncthreads();

        for (int half = 0; half < 2; ++half) {
            const int jb = j0 + half * 16;
            float s[16];
#pragma unroll
            for (int j = 0; j < 16; ++j) {
                const float* krow = &lK[(half * 16 + j) * DT_ + par * 96];
                float p0 = 0.f, p1 = 0.f, p2 = 0.f, p3 = 0.f;
#pragma unroll
                for (int k4 = 0; k4 < 96; k4 += 4) {
                    float4 kvv = *(const float4*)(krow + k4);
                    p0 += q[k4] * kvv.x;     p1 += q[k4 + 1] * kvv.y;
                    p2 += q[k4 + 2] * kvv.z; p3 += q[k4 + 3] * kvv.w;
                }
                float part = (p0 + p1) + (p2 + p3);
                part += __shfl_xor(part, 1);
                part = fminf(fmaxf(part, -1e30f), 1e30f);
                s[j] = (jb + j <= i) ? part : -1e30f;
            }
            float tm = s[0];
#pragma unroll
            for (int j = 1; j < 16; ++j) tm = fmaxf(tm, s[j]);
            float mnew  = fmaxf(mrun, tm);
            float alpha = __expf(mrun - mnew);
            mrun = mnew;
            lrun *= alpha;
#pragma unroll
            for (int d = 0; d < 64; ++d) O[d] *= alpha;
#pragma unroll
            for (int j = 0; j < 16; ++j) {
                float p = __expf(s[j] - mnew);
                lrun += p;
                const float* vr = &lV[(half * 16 + j) * DH_ + par * 64];
#pragma unroll
                for (int d4 = 0; d4 < 64; d4 += 4) {
                    float4 vvv = *(const float4*)(vr + d4);
                    O[d4] += p * vvv.x;     O[d4 + 1] += p * vvv.y;
                    O[d4 + 2] += p * vvv.z; O[d4 + 3] += p * vvv.w;
                }
            }
        }
    }
    const float inv = 1.f / fmaxf(lrun, 1e-30f);
    float* op = attn_out + ((size_t)(b * S_ + i)) * (NQ_ * DH_) + h * DH_ + par * 64;
#pragma unroll
    for (int d4 = 0; d4 < 64; d4 += 4) {
        float4 v = {cl(O[d4] * inv), cl(O[d4 + 1] * inv), cl(O[d4 + 2] * inv), cl(O[d4 + 3] * inv)};
        *(float4*)(op + d4) = v;
    }
}

// ---------------------------------------------------------------------------
extern "C" void kernel_launch(void* const* d_in, const int* in_sizes, int n_in,
                              void* d_out, int out_size, void* d_ws, size_t ws_size,
                              hipStream_t stream) {
    // Reference dtypes are float32 throughout -> fp32 pointers.
    const float* x     = (const float*)d_in[0];
    const float* cosc  = (const float*)d_in[1];
    const float* sinc  = (const float*)d_in[2];
    const int*   pos   = (const int*)d_in[3];
    // d_in[4] = attn_mask (causal tril) -- implemented analytically
    const float* W_DKV = (const float*)d_in[5];
    const float* W_UK  = (const float*)d_in[6];
    const float* W_UV  = (const float*)d_in[7];
    const float* W_DQ  = (const float*)d_in[8];
    const float* W_UQ  = (const float*)d_in[9];
    const float* W_KR  = (const float*)d_in[10];
    const float* W_QR  = (const float*)d_in[11];
    const float* W_O   = (const float*)d_in[12];

    float* outp      = (float*)d_out;            // [B,S,2048]
    float* ckv_out   = outp + 8388608;           // [B,S,512]
    float* krope_out = outp + 10485760;          // [B,NKV,S,64]

    fprintf(stderr, "[mla r5] ws_size=%zu out_size=%d n_in=%d\n", ws_size, out_size, n_in);

    // ---- flat fp32 workspace, no aliasing, total 130,023,424 B ----
    const size_t NEED = 130023424;
    if (ws_size < NEED) {
        fprintf(stderr, "[mla r5] INSUFFICIENT ws %zu < %zu\n", ws_size, NEED);
        return;
    }
    char* w = (char*)d_ws;
    auto alloc = [&](size_t bytes) { char* p = w; w += bytes; return p; };
    float* cqb   = (float*)alloc(25165824);  // [4096][1536]
    float* qcb   = (float*)alloc(33554432);  // [4096][2048]
    float* qrr   = (float*)alloc(16777216);  // [4096][1024]
    float* krr   = (float*)alloc(4194304);   // [4096][256]
    float* kcb   = (float*)alloc(8388608);   // [4096][512]
    float* vvb   = (float*)alloc(8388608);   // [4096][512]
    float* attnb = (float*)alloc(33554432);  // [4096][2048]

    // projections (direct W[K][N])
    gemm_nt<<<dim3(8, 64),  256, 0, stream>>>(x,       W_DKV, ckv_out, M_, 512,  2048); // c_kv (Output 1)
    gemm_nt<<<dim3(4, 64),  256, 0, stream>>>(x,       W_KR,  krr,     M_, 256,  2048); // K rope raw
    gemm_nt<<<dim3(24, 64), 256, 0, stream>>>(x,       W_DQ,  cqb,     M_, 1536, 2048); // c_q
    gemm_nt<<<dim3(32, 64), 256, 0, stream>>>(cqb,     W_UQ,  qcb,     M_, 2048, 1536); // Q content
    gemm_nt<<<dim3(16, 64), 256, 0, stream>>>(x,       W_QR,  qrr,     M_, 1024, 2048); // Q rope raw
    gemm_nt<<<dim3(8, 64),  256, 0, stream>>>(ckv_out, W_UK,  kcb,     M_, 512,  512);  // K content
    gemm_nt<<<dim3(8, 64),  256, 0, stream>>>(ckv_out, W_UV,  vvb,     M_, 512,  512);  // V

    // rope
    rope_q_inplace<<<8192, 256, 0, stream>>>(qrr, cosc, sinc, pos);
    rope_k<<<2048, 256, 0, stream>>>(krr, cosc, sinc, pos, krope_out);                  // Output 2

    // attention + output projection
    attn_kernel<<<dim3(16, 16, 2), 256, 0, stream>>>(qcb, qrr, kcb, krope_out, vvb, attnb);
    gemm_nt<<<dim3(32, 64), 256, 0, stream>>>(attnb, W_O, outp, M_, 2048, 2048);        // Output 0
}

// Round 6
// 2127.198 us; speedup vs baseline: 3.3483x; 3.3483x over previous
//
#include <hip/hip_runtime.h>
#include <stdint.h>

typedef unsigned short u16;
typedef unsigned int u32;

// Problem constants
#define B_    2
#define S_    2048
#define NQ_   16
#define NKV_  4
#define DH_   128
#define DR_   64
#define DT_   192
#define M_    4096   // B_*S_

using short8 = __attribute__((ext_vector_type(8))) short;
using f32x4  = __attribute__((ext_vector_type(4))) float;

__device__ __forceinline__ float cl(float f) {   // clamp diagnostic: inf/NaN -> +-3.38e38 signature
    return fminf(fmaxf(f, -3.38e38f), 3.38e38f);
}
__device__ __forceinline__ u16 f2b(float f) {    // fp32 -> bf16 RNE
    union { float f; u32 u; } v; v.f = f;
    u32 u = v.u;
    return (u16)((u + 0x7fffu + ((u >> 16) & 1u)) >> 16);
}
__device__ __forceinline__ short8 pack8(float4 a, float4 b, float s) {
    short8 r;
    r[0] = (short)f2b(a.x * s); r[1] = (short)f2b(a.y * s);
    r[2] = (short)f2b(a.z * s); r[3] = (short)f2b(a.w * s);
    r[4] = (short)f2b(b.x * s); r[5] = (short)f2b(b.y * s);
    r[6] = (short)f2b(b.z * s); r[7] = (short)f2b(b.w * s);
    return r;
}

// ---------------------------------------------------------------------------
// Tiled GEMM: C[M][N] = A[M][K] @ W[K][N], all fp32, VALU accumulate.
// (unchanged from round 5 -- proven correct)
// ---------------------------------------------------------------------------
__global__ __launch_bounds__(256) void gemm_nt(const float* __restrict__ A,
                                               const float* __restrict__ W,
                                               float* __restrict__ C,
                                               int M, int N, int K) {
    __shared__ float lA[32][64];   // [k][m]
    __shared__ float lW[32][64];   // [k][n]
    const int tid = threadIdx.x;
    const int tx = tid & 15, ty = tid >> 4;
    const int m0 = blockIdx.y * 64, n0 = blockIdx.x * 64;
    float acc[4][4] = {};

    for (int kt = 0; kt < K; kt += 32) {
        __syncthreads();
#pragma unroll
        for (int c = 0; c < 2; ++c) {
            int sg = c * 256 + tid;
            int r = sg >> 3, c4 = (sg & 7) * 4;
            float4 v = *(const float4*)(A + (size_t)(m0 + r) * K + kt + c4);
            lA[c4 + 0][r] = v.x; lA[c4 + 1][r] = v.y;
            lA[c4 + 2][r] = v.z; lA[c4 + 3][r] = v.w;
        }
#pragma unroll
        for (int c = 0; c < 2; ++c) {
            int sg = c * 256 + tid;
            int rr = sg >> 4, n4 = (sg & 15) * 4;
            *(float4*)&lW[rr][n4] = *(const float4*)(W + (size_t)(kt + rr) * N + n0 + n4);
        }
        __syncthreads();
#pragma unroll
        for (int kk = 0; kk < 32; ++kk) {
            float4 a4 = *(const float4*)&lA[kk][ty * 4];
            float4 w4 = *(const float4*)&lW[kk][tx * 4];
            float a[4] = {a4.x, a4.y, a4.z, a4.w};
            float w[4] = {w4.x, w4.y, w4.z, w4.w};
#pragma unroll
            for (int i = 0; i < 4; ++i)
#pragma unroll
                for (int j = 0; j < 4; ++j)
                    acc[i][j] += a[i] * w[j];
        }
    }
#pragma unroll
    for (int i = 0; i < 4; ++i) {
        float* cp = C + (size_t)(m0 + ty * 4 + i) * N + n0 + tx * 4;
        float4 v = {cl(acc[i][0]), cl(acc[i][1]), cl(acc[i][2]), cl(acc[i][3])};
        *(float4*)cp = v;
    }
}

// ---------------------------------------------------------------------------
// RoPE Q, in place on qr[(b,s)][h*64+d] (fp32)
// ---------------------------------------------------------------------------
__global__ __launch_bounds__(256) void rope_q_inplace(float* __restrict__ qr,
                                                      const float* __restrict__ cosc,
                                                      const float* __restrict__ sinc,
                                                      const int* __restrict__ pos) {
    int t = blockIdx.x * 256 + threadIdx.x;          // t < 4096*16*32
    int d = t & 31, h = (t >> 5) & 15, rowi = t >> 9;
    int s = rowi & 2047;
    int p = pos[s];
    float c1 = cosc[p * 64 + d],      s1 = sinc[p * 64 + d];
    float c2 = cosc[p * 64 + 32 + d], s2 = sinc[p * 64 + 32 + d];
    float* base = qr + (size_t)rowi * 1024 + h * 64;
    float x1 = base[d];
    float x2 = base[d + 32];
    base[d]      = x1 * c1 - x2 * s1;   // out = x*cos + rotate_half(x)*sin
    base[d + 32] = x2 * c2 + x1 * s2;
}

// RoPE K: krr[(b,s)][kv*64+d] -> Krope[b][kv][s][64]  (= Output 2)
__global__ __launch_bounds__(256) void rope_k(const float* __restrict__ krr,
                                              const float* __restrict__ cosc,
                                              const float* __restrict__ sinc,
                                              const int* __restrict__ pos,
                                              float* __restrict__ Krope) {
    int t = blockIdx.x * 256 + threadIdx.x;          // t < 4096*4*32
    int d = t & 31, kv = (t >> 5) & 3, rowi = t >> 7;
    int b = rowi >> 11, s = rowi & 2047;
    int p = pos[s];
    float c1 = cosc[p * 64 + d],      s1 = sinc[p * 64 + d];
    float c2 = cosc[p * 64 + 32 + d], s2 = sinc[p * 64 + 32 + d];
    float x1 = krr[(size_t)rowi * 256 + kv * 64 + d];
    float x2 = krr[(size_t)rowi * 256 + kv * 64 + 32 + d];
    size_t ob = ((size_t)((b * NKV_ + kv) * S_) + s) * 64;
    Krope[ob + d]      = cl(x1 * c1 - x2 * s1);
    Krope[ob + 32 + d] = cl(x2 * c2 + x1 * s2);
}

// ---------------------------------------------------------------------------
// pack_k: Kp bf16 [g=(b*4+kv)][s][192] <- kcb fp32 [(b,s)][kv*128+d] + krope fp32 [g][s][64]
// ---------------------------------------------------------------------------
__global__ __launch_bounds__(256) void pack_k(const float* __restrict__ kcb,
                                              const float* __restrict__ krope,
                                              u16* __restrict__ Kp) {
    int t = blockIdx.x * 256 + threadIdx.x;          // t < 16384*24
    int c8 = (t % 24) * 8;
    int r  = t / 24;                                  // r = g*2048 + s
    int g = r >> 11, s = r & 2047;
    int b = g >> 2, kv = g & 3;
    const float* src;
    if (c8 < 128) src = kcb + ((size_t)(b * S_ + s)) * 512 + kv * 128 + c8;
    else          src = krope + ((size_t)g * S_ + s) * 64 + (c8 - 128);
    float4 v0 = *(const float4*)src;
    float4 v1 = *(const float4*)(src + 4);
    short8 p = pack8(v0, v1, 1.f);
    *(short8*)(Kp + (size_t)r * 192 + c8) = p;
}

// ---------------------------------------------------------------------------
// transpose_vt: Vt bf16 [g][d=128][s=2048] <- vvb fp32 [(b,s)][kv*128+d]
// block (32,8), grid (64, 4, 8)
// ---------------------------------------------------------------------------
__global__ __launch_bounds__(256) void transpose_vt(const float* __restrict__ vvb,
                                                    u16* __restrict__ Vt) {
    __shared__ float tile[32][33];
    int s0 = blockIdx.x * 32, d0 = blockIdx.y * 32, g = blockIdx.z;
    int b = g >> 2, kv = g & 3;
    int tx = threadIdx.x, ty = threadIdx.y;
#pragma unroll
    for (int i = 0; i < 32; i += 8)
        tile[ty + i][tx] = vvb[((size_t)(b * S_ + s0 + ty + i)) * 512 + kv * 128 + d0 + tx];
    __syncthreads();
#pragma unroll
    for (int i = 0; i < 32; i += 8)
        Vt[((size_t)g * 128 + d0 + ty + i) * S_ + s0 + tx] = f2b(tile[tx][ty + i]);
}

// ---------------------------------------------------------------------------
// MFMA flash attention. Block = 4 waves = 64 q-rows of one (b,h).
// grid (32 qtiles [reversed: heavy first], 16 heads, 2 batch).
// Q from qc/qr fp32 (converted to bf16 frags, pre-scaled); K from Kp bf16;
// V from Vt bf16 (transposed). Causal. Out: attn_out fp32 [(b,s)][h*128+d].
// Layouts [m89/m91/m120 verified]: A-frag A[m=lane&15][k=quad*8+j];
// B-frag B[n=lane&15][k=quad*8+j]; C/D col=lane&15, row=quad*4+reg.
// ---------------------------------------------------------------------------
__global__ __launch_bounds__(256) void attn_mfma(const float* __restrict__ qc,
                                                 const float* __restrict__ qr,
                                                 const u16* __restrict__ Kp,
                                                 const u16* __restrict__ Vt,
                                                 float* __restrict__ attn_out) {
    __shared__ __align__(16) u16 lK[32 * 200];     // 32 kv-rows x 192 (+8 pad)
    __shared__ __align__(16) u16 lVt[128 * 40];    // 128 d-rows x 32 (+8 pad)
    __shared__ __align__(16) u16 lP[4][16 * 40];   // per-wave P 16x32 (+8 pad)

    const int t = threadIdx.x, lane = t & 63, w = t >> 6;
    const int quad = lane >> 4, l16 = lane & 15;
    const int qt = 31 - (int)blockIdx.x;           // heavy blocks first
    const int h = blockIdx.y, b = blockIdx.z;
    const int g = b * NKV_ + (h >> 2);
    const int q0 = qt * 64;
    const int iw = q0 + w * 16;                    // wave's q-row base
    const float sc = 0.07216878364870322f;         // 1/sqrt(192)

    // Q fragments: rows m=l16, k-chunks of 32 (content 0..127, rope 128..191)
    short8 qf[6];
    {
        const int irow = iw + l16;
#pragma unroll
        for (int kc = 0; kc < 6; ++kc) {
            const float* src = (kc < 4)
                ? qc + ((size_t)(b * S_ + irow)) * 2048 + h * 128 + kc * 32 + quad * 8
                : qr + ((size_t)(b * S_ + irow)) * 1024 + h * 64 + (kc - 4) * 32 + quad * 8;
            float4 v0 = *(const float4*)src;
            float4 v1 = *(const float4*)(src + 4);
            qf[kc] = pack8(v0, v1, sc);
        }
    }

    f32x4 O8[8] = {};                               // O: n-chunks of d (8 x 16), C layout
    float mr[4] = {-1e30f, -1e30f, -1e30f, -1e30f};
    float lr[4] = {0.f, 0.f, 0.f, 0.f};

    const int ntile = qt * 2 + 2;
    for (int tile = 0; tile < ntile; ++tile) {
        const int j0 = tile * 32;
        __syncthreads();
        // stage K tile: 32 rows x 192 u16 = 768 x 16B, 3/thread
#pragma unroll
        for (int c = 0; c < 3; ++c) {
            int seg = c * 256 + t;
            int row = seg / 24, ch = (seg % 24) * 8;
            *(uint4*)&lK[row * 200 + ch] =
                *(const uint4*)&Kp[((size_t)g * S_ + j0 + row) * 192 + ch];
        }
        // stage Vt tile: 128 d-rows x 32 u16 = 512 x 16B, 2/thread
#pragma unroll
        for (int c = 0; c < 2; ++c) {
            int seg = c * 256 + t;
            int d = seg >> 2, ch = (seg & 3) * 8;
            *(uint4*)&lVt[d * 40 + ch] =
                *(const uint4*)&Vt[((size_t)g * 128 + d) * S_ + j0 + ch];
        }
        __syncthreads();

        if (j0 <= iw + 15) {                        // wave has unmasked rows
            // S = Q K^T for two 16-col chunks
            f32x4 s0 = {}, s1 = {};
#pragma unroll
            for (int kc = 0; kc < 6; ++kc) {
                short8 k0 = *(const short8*)&lK[l16 * 200 + kc * 32 + quad * 8];
                s0 = __builtin_amdgcn_mfma_f32_16x16x32_bf16(qf[kc], k0, s0, 0, 0, 0);
            }
#pragma unroll
            for (int kc = 0; kc < 6; ++kc) {
                short8 k1 = *(const short8*)&lK[(16 + l16) * 200 + kc * 32 + quad * 8];
                s1 = __builtin_amdgcn_mfma_f32_16x16x32_bf16(qf[kc], k1, s1, 0, 0, 0);
            }
            // causal mask; rows ir = iw + quad*4 + r, cols j0 + nc*16 + l16
            float sv[8];
#pragma unroll
            for (int r = 0; r < 4; ++r) {
                int ir = iw + quad * 4 + r;
                sv[r]     = (j0 + l16      <= ir) ? s0[r] : -1e30f;
                sv[4 + r] = (j0 + 16 + l16 <= ir) ? s1[r] : -1e30f;
            }
            // row max across the 16-lane group
            float tm[4];
#pragma unroll
            for (int r = 0; r < 4; ++r) tm[r] = fmaxf(sv[r], sv[4 + r]);
#pragma unroll
            for (int m = 1; m < 16; m <<= 1)
#pragma unroll
                for (int r = 0; r < 4; ++r) tm[r] = fmaxf(tm[r], __shfl_xor(tm[r], m));
            // online softmax update
            float al[4], p[8];
#pragma unroll
            for (int r = 0; r < 4; ++r) {
                float mn = fmaxf(mr[r], tm[r]);
                al[r] = __expf(mr[r] - mn);
                mr[r] = mn;
                p[r]     = __expf(sv[r] - mn);
                p[4 + r] = __expf(sv[4 + r] - mn);
            }
            float ps[4];
#pragma unroll
            for (int r = 0; r < 4; ++r) ps[r] = p[r] + p[4 + r];
#pragma unroll
            for (int m = 1; m < 16; m <<= 1)
#pragma unroll
                for (int r = 0; r < 4; ++r) ps[r] += __shfl_xor(ps[r], m);
#pragma unroll
            for (int r = 0; r < 4; ++r) lr[r] = lr[r] * al[r] + ps[r];
#pragma unroll
            for (int dc = 0; dc < 8; ++dc)
#pragma unroll
                for (int r = 0; r < 4; ++r) O8[dc][r] *= al[r];
            // P (C layout) -> LDS -> A-layout frag
#pragma unroll
            for (int r = 0; r < 4; ++r) {
                lP[w][(quad * 4 + r) * 40 + l16]      = f2b(p[r]);
                lP[w][(quad * 4 + r) * 40 + 16 + l16] = f2b(p[4 + r]);
            }
            short8 pf = *(const short8*)&lP[w][l16 * 40 + quad * 8];
            // O += P V  (B-frag from Vt rows: n=d, k=kv-pos)
#pragma unroll
            for (int dc = 0; dc < 8; ++dc) {
                short8 vf = *(const short8*)&lVt[(dc * 16 + l16) * 40 + quad * 8];
                O8[dc] = __builtin_amdgcn_mfma_f32_16x16x32_bf16(pf, vf, O8[dc], 0, 0, 0);
            }
        }
    }
    // epilogue: normalize, write fp32 [(b,s)][h*128+d]
    float inv[4];
#pragma unroll
    for (int r = 0; r < 4; ++r) inv[r] = 1.f / fmaxf(lr[r], 1e-30f);
#pragma unroll
    for (int dc = 0; dc < 8; ++dc)
#pragma unroll
        for (int r = 0; r < 4; ++r) {
            int ir = iw + quad * 4 + r;
            attn_out[((size_t)(b * S_ + ir)) * 2048 + h * 128 + dc * 16 + l16] =
                cl(O8[dc][r] * inv[r]);
        }
}

// ---------------------------------------------------------------------------
extern "C" void kernel_launch(void* const* d_in, const int* in_sizes, int n_in,
                              void* d_out, int out_size, void* d_ws, size_t ws_size,
                              hipStream_t stream) {
    const float* x     = (const float*)d_in[0];
    const float* cosc  = (const float*)d_in[1];
    const float* sinc  = (const float*)d_in[2];
    const int*   pos   = (const int*)d_in[3];
    // d_in[4] = attn_mask (causal tril) -- implemented analytically
    const float* W_DKV = (const float*)d_in[5];
    const float* W_UK  = (const float*)d_in[6];
    const float* W_UV  = (const float*)d_in[7];
    const float* W_DQ  = (const float*)d_in[8];
    const float* W_UQ  = (const float*)d_in[9];
    const float* W_KR  = (const float*)d_in[10];
    const float* W_QR  = (const float*)d_in[11];
    const float* W_O   = (const float*)d_in[12];

    float* outp      = (float*)d_out;            // [B,S,2048]
    float* ckv_out   = outp + 8388608;           // [B,S,512]
    float* krope_out = outp + 10485760;          // [B,NKV,S,64]

    // ---- flat fp32/bf16 workspace, no aliasing ----
    char* w = (char*)d_ws;
    auto alloc = [&](size_t bytes) { char* p = w; w += bytes; return p; };
    float* cqb   = (float*)alloc(25165824);  // [4096][1536]
    float* qcb   = (float*)alloc(33554432);  // [4096][2048]
    float* qrr   = (float*)alloc(16777216);  // [4096][1024]
    float* krr   = (float*)alloc(4194304);   // [4096][256]
    float* kcb   = (float*)alloc(8388608);   // [4096][512]
    float* vvb   = (float*)alloc(8388608);   // [4096][512]
    float* attnb = (float*)alloc(33554432);  // [4096][2048]
    u16*   Kp    = (u16*)alloc(6291456);     // [8][2048][192] bf16
    u16*   Vt    = (u16*)alloc(4194304);     // [8][128][2048] bf16
    (void)ws_size;

    // projections (direct W[K][N])
    gemm_nt<<<dim3(8, 64),  256, 0, stream>>>(x,       W_DKV, ckv_out, M_, 512,  2048); // c_kv (Output 1)
    gemm_nt<<<dim3(4, 64),  256, 0, stream>>>(x,       W_KR,  krr,     M_, 256,  2048); // K rope raw
    gemm_nt<<<dim3(24, 64), 256, 0, stream>>>(x,       W_DQ,  cqb,     M_, 1536, 2048); // c_q
    gemm_nt<<<dim3(32, 64), 256, 0, stream>>>(cqb,     W_UQ,  qcb,     M_, 2048, 1536); // Q content
    gemm_nt<<<dim3(16, 64), 256, 0, stream>>>(x,       W_QR,  qrr,     M_, 1024, 2048); // Q rope raw
    gemm_nt<<<dim3(8, 64),  256, 0, stream>>>(ckv_out, W_UK,  kcb,     M_, 512,  512);  // K content
    gemm_nt<<<dim3(8, 64),  256, 0, stream>>>(ckv_out, W_UV,  vvb,     M_, 512,  512);  // V

    // rope
    rope_q_inplace<<<8192, 256, 0, stream>>>(qrr, cosc, sinc, pos);
    rope_k<<<2048, 256, 0, stream>>>(krr, cosc, sinc, pos, krope_out);                  // Output 2

    // pack K / V for MFMA attention
    pack_k<<<1536, 256, 0, stream>>>(kcb, krope_out, Kp);
    transpose_vt<<<dim3(64, 4, 8), dim3(32, 8), 0, stream>>>(vvb, Vt);

    // attention + output projection
    attn_mfma<<<dim3(32, 16, 2), 256, 0, stream>>>(qcb, qrr, Kp, Vt, attnb);
    gemm_nt<<<dim3(32, 64), 256, 0, stream>>>(attnb, W_O, outp, M_, 2048, 2048);        // Output 0
}